// Round 11
// baseline (585.728 us; speedup 1.0000x reference)
//
#include <hip/hip_runtime.h>
#include <hip/hip_bf16.h>

#define Bb 128
#define Tt 1024
#define Nn 128
#define Ss 256
#define NEGF (-1e30f)
#define D9 9.0f   // fixed log-domain shift per step; absorbed as D9*(len-1) at the end

typedef __attribute__((ext_vector_type(8))) short short8;  // 8 bf16 = 4 VGPRs (MFMA A/B frag)
typedef __attribute__((ext_vector_type(4))) float f32x4;   // MFMA C/D frag

__device__ __forceinline__ short bf16b(float f) {
    __hip_bfloat16 h = __float2bfloat16(f);
    return *reinterpret_cast<short*>(&h);
}
__device__ __forceinline__ int pk2(float lo, float hi) {
    return (int)(((unsigned int)(unsigned short)bf16b(lo)) |
                 ((unsigned int)(unsigned short)bf16b(hi) << 16));
}

#define MFMA16(A, B, C) __builtin_amdgcn_mfma_f32_16x16x32_bf16((A), (B), (C), 0, 0, 0)

// ---- FCC per-step body: 2-wave group, wave h owns rows 64h..64h+63 (4 m-tiles).
// E tiles row-interleaved so each lane's 16 outputs are contiguous rows
// lbase..lbase+15 (identity-order u array in LDS). Step order tuned for overlap:
// ds_reads -> ring exps (overlap read latency) -> refill loads (max drain overlap)
// -> MFMA -> epilogue. Free-running u + ones colsum + (S,C) snapshot at t==leng.
#define FCC_STEP(t_, k_)                                                       \
    {                                                                          \
        const int t = (t_);                                                    \
        /* 1. B-frags of u_{t-1} (LDS, issue first) */                         \
        const short* ub = ubuf[(t - 1) & 1] + g * 136 + quad * 8;              \
        short8 bf0 = *(const short8*)(ub);                                     \
        short8 bf1 = *(const short8*)(ub + 32);                                \
        short8 bf2 = *(const short8*)(ub + 64);                                \
        short8 bf3 = *(const short8*)(ub + 96);                                \
        /* 2. wc for THIS step from ring slot t&1 (exps overlap LDS latency) */\
        const int sl = (t_) & 1;                                               \
        float wc[16];                                                          \
        {                                                                      \
            float4 v0 = xs[sl][0], v1 = xs[sl][1], v2 = xs[sl][2], v3 = xs[sl][3]; \
            wc[0]  = __expf(v0.x - D9); wc[1]  = __expf(v0.y - D9);            \
            wc[2]  = __expf(v0.z - D9); wc[3]  = __expf(v0.w - D9);            \
            wc[4]  = __expf(v1.x - D9); wc[5]  = __expf(v1.y - D9);            \
            wc[6]  = __expf(v1.z - D9); wc[7]  = __expf(v1.w - D9);            \
            wc[8]  = __expf(v2.x - D9); wc[9]  = __expf(v2.y - D9);            \
            wc[10] = __expf(v2.z - D9); wc[11] = __expf(v2.w - D9);            \
            wc[12] = __expf(v3.x - D9); wc[13] = __expf(v3.y - D9);            \
            wc[14] = __expf(v3.z - D9); wc[15] = __expf(v3.w - D9);            \
        }                                                                      \
        float mren = 0.0f;                                                     \
        if ((k_) == 0) { /* renorm apply (measured at prev k==7) */            \
            mren = fmaxf(wredp[0][g], wredp[1][g]);                            \
            float invm = 1.0f / mren;                                          \
            _Pragma("unroll")                                                  \
            for (int i = 0; i < 16; ++i) wc[i] *= invm;                        \
        }                                                                      \
        /* 3. refill ring slot with x[t+2] (early issue -> overlaps MFMA) */   \
        {                                                                      \
            int kk = t + 2; if (kk > Tt - 1) kk = Tt - 1;                      \
            const float* xr_ = xb + (size_t)kk * Nn + lbase;                   \
            xs[sl][0] = *(const float4*)(xr_);                                 \
            xs[sl][1] = *(const float4*)(xr_ + 4);                             \
            xs[sl][2] = *(const float4*)(xr_ + 8);                             \
            xs[sl][3] = *(const float4*)(xr_ + 12);                            \
        }                                                                      \
        /* 4. MFMA: 4 m-tiles x 4 k-chunks (+ colsum on wave 0) */             \
        f32x4 a0 = {0.f,0.f,0.f,0.f}, a1 = {0.f,0.f,0.f,0.f};                  \
        f32x4 a2 = {0.f,0.f,0.f,0.f}, a3 = {0.f,0.f,0.f,0.f};                  \
        a0 = MFMA16(ea[0][0], bf0, a0); a1 = MFMA16(ea[1][0], bf0, a1);        \
        a2 = MFMA16(ea[2][0], bf0, a2); a3 = MFMA16(ea[3][0], bf0, a3);        \
        a0 = MFMA16(ea[0][1], bf1, a0); a1 = MFMA16(ea[1][1], bf1, a1);        \
        a2 = MFMA16(ea[2][1], bf1, a2); a3 = MFMA16(ea[3][1], bf1, a3);        \
        a0 = MFMA16(ea[0][2], bf2, a0); a1 = MFMA16(ea[1][2], bf2, a1);        \
        a2 = MFMA16(ea[2][2], bf2, a2); a3 = MFMA16(ea[3][2], bf2, a3);        \
        a0 = MFMA16(ea[0][3], bf3, a0); a1 = MFMA16(ea[1][3], bf3, a1);        \
        a2 = MFMA16(ea[2][3], bf3, a2); a3 = MFMA16(ea[3][3], bf3, a3);        \
        if (h == 0) { /* colsum(u_{t-1}); snapshot BEFORE c update */          \
            f32x4 aS = {0.f,0.f,0.f,0.f};                                      \
            aS = MFMA16(ones, bf0, aS); aS = MFMA16(ones, bf1, aS);            \
            aS = MFMA16(ones, bf2, aS); aS = MFMA16(ones, bf3, aS);            \
            if (t == leng) { Sreg = aS[0]; Creg = c; }                         \
        }                                                                      \
        if ((k_) == 0) c += __logf(mren);                                      \
        /* 5. un = wc * acc -> pack bf16 -> 2x ds_write_b128 (contig 32B) */   \
        float un[16];                                                          \
        un[0]  = wc[0]  * a0[0]; un[1]  = wc[1]  * a0[1];                      \
        un[2]  = wc[2]  * a0[2]; un[3]  = wc[3]  * a0[3];                      \
        un[4]  = wc[4]  * a1[0]; un[5]  = wc[5]  * a1[1];                      \
        un[6]  = wc[6]  * a1[2]; un[7]  = wc[7]  * a1[3];                      \
        un[8]  = wc[8]  * a2[0]; un[9]  = wc[9]  * a2[1];                      \
        un[10] = wc[10] * a2[2]; un[11] = wc[11] * a2[3];                      \
        un[12] = wc[12] * a3[0]; un[13] = wc[13] * a3[1];                      \
        un[14] = wc[14] * a3[2]; un[15] = wc[15] * a3[3];                      \
        {                                                                      \
            int4 dw0, dw1;                                                     \
            dw0.x = pk2(un[0],  un[1]);  dw0.y = pk2(un[2],  un[3]);           \
            dw0.z = pk2(un[4],  un[5]);  dw0.w = pk2(un[6],  un[7]);           \
            dw1.x = pk2(un[8],  un[9]);  dw1.y = pk2(un[10], un[11]);          \
            dw1.z = pk2(un[12], un[13]); dw1.w = pk2(un[14], un[15]);          \
            int4* wp = (int4*)(ubuf[t & 1] + g * 136 + lbase);                 \
            wp[0] = dw0; wp[1] = dw1;                                          \
        }                                                                      \
        if ((k_) == 7) { /* renorm measure: per-col max of un */               \
            float mm = un[0];                                                  \
            _Pragma("unroll")                                                  \
            for (int i = 1; i < 16; ++i) mm = fmaxf(mm, un[i]);                \
            mm = fmaxf(mm, __shfl_xor(mm, 16));                                \
            mm = fmaxf(mm, __shfl_xor(mm, 32));                                \
            if (lane < 16) wredp[h][lane] = mm;                                \
        }                                                                      \
        __syncthreads();                                                       \
    }

// ---- FAC per-step body (R6-verified: no barriers, direct-load em ring) ----
#define FAC_STEP(t_, k_)                                                       \
    {                                                                          \
        const int t = (t_);                                                    \
        const int d = ((k_) + 7) & 7;                                          \
        float e0 = em[d][0], e1 = em[d][1], e2 = em[d][2], e3 = em[d][3];      \
        int tn = t + 8; if (tn > Tt - 1) tn = Tt - 1;                          \
        const float* xrow = xb + (size_t)tn * Nn;                              \
        em[d][0] = xrow[tgi[0]]; em[d][1] = xrow[tgi[1]];                      \
        em[d][2] = xrow[tgi[2]]; em[d][3] = xrow[tgi[3]];                      \
        float bup = __shfl_up(bt[3], 1);                                       \
        float prev0 = (lane == 0) ? NEGF : bup;                                \
        float nb[4];                                                           \
        {                                                                      \
            float aa = bt[0] + st[0], bb = prev0 + ntr[0];                     \
            float hi = fmaxf(aa, bb), lo = fminf(aa, bb);                      \
            nb[0] = e0 + hi + __logf(1.0f + __expf(lo - hi));                  \
        }                                                                      \
        {                                                                      \
            float aa = bt[1] + st[1], bb = bt[0] + ntr[1];                     \
            float hi = fmaxf(aa, bb), lo = fminf(aa, bb);                      \
            nb[1] = e1 + hi + __logf(1.0f + __expf(lo - hi));                  \
        }                                                                      \
        {                                                                      \
            float aa = bt[2] + st[2], bb = bt[1] + ntr[2];                     \
            float hi = fmaxf(aa, bb), lo = fminf(aa, bb);                      \
            nb[2] = e2 + hi + __logf(1.0f + __expf(lo - hi));                  \
        }                                                                      \
        {                                                                      \
            float aa = bt[3] + st[3], bb = bt[2] + ntr[3];                     \
            float hi = fmaxf(aa, bb), lo = fminf(aa, bb);                      \
            nb[3] = e3 + hi + __logf(1.0f + __expf(lo - hi));                  \
        }                                                                      \
        if (t < len) {                                                         \
            bt[0] = nb[0]; bt[1] = nb[1]; bt[2] = nb[2]; bt[3] = nb[3];        \
        }                                                                      \
    }

// 128-thread blocks (2 waves). blocks 0..7: FCC (one 16-batch group, 2 waves).
// blocks 8..71: FAC (2 batches, 1 wave each, no barriers).
__global__ __launch_bounds__(128) void asg_main(
    const float* __restrict__ trans, const float* __restrict__ x,
    const int* __restrict__ targets, const int* __restrict__ ilen,
    const int* __restrict__ tlen,
    float* __restrict__ fcc_out, float* __restrict__ fac_out)
{
    __shared__ __align__(16) short uts[2][16][136];  // [buf][g][j], row 272B
    __shared__ float wred[2][16];

    const int tid  = threadIdx.x;
    const int h    = tid >> 6;      // wave in block (0/1)
    const int lane = tid & 63;

    if (blockIdx.x < 8) {
        // ================= FCC =================
        const int g     = lane & 15;       // batch col
        const int quad  = lane >> 4;
        const int lbase = 64 * h + 16 * quad;  // this lane's 16 contiguous rows
        const int b     = (int)blockIdx.x * 16 + g;
        const int leng  = ilen[b];
        const float* xb = x + (size_t)b * Tt * Nn;

        short* ubuf[2] = { &uts[0][0][0], &uts[1][0][0] };
        float (*wredp)[16] = wred;

        // E A-frags, row-interleaved: tile mtl row m=(lane&15) holds true row
        // jr = 64h + 16*(m>>2) + 4*mtl + (m&3)  -> lane outputs land contiguous.
        short8 ea[4][4];
        #pragma unroll
        for (int mtl = 0; mtl < 4; ++mtl) {
            const int jr = 64 * h + 16 * (g >> 2) + 4 * mtl + (g & 3);
            const float* tr = trans + (size_t)jr * Nn + quad * 8;
            #pragma unroll
            for (int kc = 0; kc < 4; ++kc) {
                short8 v;
                #pragma unroll
                for (int jj = 0; jj < 8; ++jj) v[jj] = bf16b(__expf(tr[kc * 32 + jj]));
                ea[mtl][kc] = v;
            }
        }
        short8 ones;
        #pragma unroll
        for (int jj = 0; jj < 8; ++jj) ones[jj] = (short)0x3F80;  // bf16 1.0

        // u0 = exp(x[0]) -> buf0 (c = 0); lane writes rows lbase..lbase+15 of col g
        {
            const float* x0 = xb + lbase;
            int4 dw0, dw1;
            dw0.x = pk2(__expf(x0[0]),  __expf(x0[1]));
            dw0.y = pk2(__expf(x0[2]),  __expf(x0[3]));
            dw0.z = pk2(__expf(x0[4]),  __expf(x0[5]));
            dw0.w = pk2(__expf(x0[6]),  __expf(x0[7]));
            dw1.x = pk2(__expf(x0[8]),  __expf(x0[9]));
            dw1.y = pk2(__expf(x0[10]), __expf(x0[11]));
            dw1.z = pk2(__expf(x0[12]), __expf(x0[13]));
            dw1.w = pk2(__expf(x0[14]), __expf(x0[15]));
            int4* wp = (int4*)(ubuf[0] + g * 136 + lbase);
            wp[0] = dw0; wp[1] = dw1;
        }

        // ring depth 2: slot t&1 holds x[t];  init slot1 <- x[1], slot0 <- x[2]
        float4 xs[2][4];
        #pragma unroll
        for (int k = 1; k <= 2; ++k) {
            const float* xr_ = xb + (size_t)k * Nn + lbase;
            #pragma unroll
            for (int i = 0; i < 4; ++i) xs[k & 1][i] = *(const float4*)(xr_ + 4 * i);
        }
        float c = 0.0f, Sreg = 1.0f, Creg = 0.0f;
        __syncthreads();

        #pragma unroll
        for (int k = 1; k < 8; ++k) FCC_STEP(k, k)
        for (int tb = 8; tb < Tt; tb += 8) {
            #pragma unroll
            for (int k = 0; k < 8; ++k) FCC_STEP(tb + k, k)
        }

        // tail t = 1024: colsum(u_1023) covers leng == Tt
        if (h == 0) {
            const short* ub = ubuf[1] + g * 136 + quad * 8;  // 1023 & 1 == 1
            short8 bf0 = *(const short8*)(ub);
            short8 bf1 = *(const short8*)(ub + 32);
            short8 bf2 = *(const short8*)(ub + 64);
            short8 bf3 = *(const short8*)(ub + 96);
            f32x4 aS = {0.f,0.f,0.f,0.f};
            aS = MFMA16(ones, bf0, aS); aS = MFMA16(ones, bf1, aS);
            aS = MFMA16(ones, bf2, aS); aS = MFMA16(ones, bf3, aS);
            if (leng == Tt) { Sreg = aS[0]; Creg = c; }
            if (quad == 0)
                fcc_out[b] = Creg + __logf(Sreg) + D9 * (float)(leng - 1);
        }
    } else {
        // ================= FAC (1 wave per batch, no barriers) =================
        const int b   = ((int)blockIdx.x - 8) * 2 + h;
        const int len = ilen[b];
        const int tl  = tlen[b];
        const float* xb = x + (size_t)b * Tt * Nn;

        int   tgi[4];
        float st[4], ntr[4], bt[4];
        #pragma unroll
        for (int r = 0; r < 4; ++r) {
            const int s = (lane << 2) + r;
            const int tgv = targets[b * Ss + s];
            const int pg  = (s == 0) ? tgv : targets[b * Ss + s - 1];
            tgi[r] = tgv;
            st[r]  = trans[tgv * Nn + tgv];
            ntr[r] = trans[tgv * Nn + pg];
            bt[r]  = (s == 0) ? xb[tgv] : NEGF;
        }
        float em[8][4];
        #pragma unroll
        for (int k = 1; k <= 8; ++k) {
            int tt = k; if (tt > Tt - 1) tt = Tt - 1;
            const float* xrow = xb + (size_t)tt * Nn;
            em[(k - 1) & 7][0] = xrow[tgi[0]];
            em[(k - 1) & 7][1] = xrow[tgi[1]];
            em[(k - 1) & 7][2] = xrow[tgi[2]];
            em[(k - 1) & 7][3] = xrow[tgi[3]];
        }
        #pragma unroll
        for (int k = 1; k < 8; ++k) FAC_STEP(k, k)
        for (int tb = 8; tb < Tt; tb += 8) {
            #pragma unroll
            for (int k = 0; k < 8; ++k) FAC_STEP(tb + k, k)
        }
        #pragma unroll
        for (int r = 0; r < 4; ++r)
            if ((lane << 2) + r == tl - 1) fac_out[b] = bt[r];
    }
}

__global__ __launch_bounds__(128) void reduce_kernel(const float* __restrict__ fcc,
                                                     const float* __restrict__ fac,
                                                     float* __restrict__ out) {
    __shared__ float r2[2];
    int tid = threadIdx.x;
    float v = fcc[tid] - fac[tid];
    #pragma unroll
    for (int o = 32; o > 0; o >>= 1) v += __shfl_xor(v, o);
    if ((tid & 63) == 0) r2[tid >> 6] = v;
    __syncthreads();
    if (tid == 0) out[0] = (r2[0] + r2[1]) * (1.0f / Bb);
}

extern "C" void kernel_launch(void* const* d_in, const int* in_sizes, int n_in,
                              void* d_out, int out_size, void* d_ws, size_t ws_size,
                              hipStream_t stream) {
    const float* trans   = (const float*)d_in[0];
    const float* x       = (const float*)d_in[1];
    const int*   targets = (const int*)d_in[2];
    const int*   ilen    = (const int*)d_in[3];
    const int*   tlen    = (const int*)d_in[4];
    float* out = (float*)d_out;

    float* fcc = (float*)d_ws;       // 128 floats
    float* fac = fcc + Bb;           // 128 floats

    asg_main<<<72, 128, 0, stream>>>(trans, x, targets, ilen, tlen, fcc, fac);
    reduce_kernel<<<1, 128, 0, stream>>>(fcc, fac, out);
}

// Round 12
// 392.147 us; speedup vs baseline: 1.4936x; 1.4936x over previous
//
#include <hip/hip_runtime.h>
#include <hip/hip_bf16.h>

#define Bb 128
#define Tt 1024
#define Nn 128
#define Ss 256
#define NEGF (-1e30f)
#define D9 9.0f   // fixed log-domain shift per active step (absorbed into c at the end)

typedef __attribute__((ext_vector_type(8))) short short8;  // 8 bf16 (4 VGPRs) — MFMA A/B frag
typedef __attribute__((ext_vector_type(4))) float f32x4;   // MFMA C/D frag

__device__ __forceinline__ short bf16b(float f) {
    __hip_bfloat16 h = __float2bfloat16(f);
    return *reinterpret_cast<short*>(&h);
}

// ---- FCC per-step body (R6-verified, unchanged). t_ = tb + k_ (tb%8==0),
// k_ compile-time -> ring indices fold to constants; ring slots refilled by
// DIRECT global->register loads, consumed 4 steps later.
#define FCC_STEP(t_, k_)                                                       \
    {                                                                          \
        const int t = (t_);                                                    \
        if ((k_) == 0) { /* renorm apply: wred written at k==7, post-barrier */\
            float m = fmaxf(fmaxf(wred[0][g], wred[1][g]),                     \
                            fmaxf(wred[2][g], wred[3][g]));                    \
            if (t < len) {                                                     \
                float invm = 1.0f / m;                                         \
                wc[0][0] *= invm; wc[0][1] *= invm;                            \
                wc[0][2] *= invm; wc[0][3] *= invm;                            \
                wc[1][0] *= invm; wc[1][1] *= invm;                            \
                wc[1][2] *= invm; wc[1][3] *= invm;                            \
                c += __logf(m);                                                \
            }                                                                  \
        }                                                                      \
        const short* up = &ut[(t - 1) & 1][g][0] + quad * 8;                   \
        short8 bf0 = *(const short8*)(up);                                     \
        short8 bf1 = *(const short8*)(up + 32);                                \
        short8 bf2 = *(const short8*)(up + 64);                                \
        short8 bf3 = *(const short8*)(up + 96);                                \
        f32x4 a0p = {0.f, 0.f, 0.f, 0.f}, a0q = {0.f, 0.f, 0.f, 0.f};          \
        f32x4 a1p = {0.f, 0.f, 0.f, 0.f}, a1q = {0.f, 0.f, 0.f, 0.f};          \
        a0p = __builtin_amdgcn_mfma_f32_16x16x32_bf16(ea[0][0], bf0, a0p, 0, 0, 0); \
        a1p = __builtin_amdgcn_mfma_f32_16x16x32_bf16(ea[1][0], bf0, a1p, 0, 0, 0); \
        a0q = __builtin_amdgcn_mfma_f32_16x16x32_bf16(ea[0][2], bf2, a0q, 0, 0, 0); \
        a1q = __builtin_amdgcn_mfma_f32_16x16x32_bf16(ea[1][2], bf2, a1q, 0, 0, 0); \
        a0p = __builtin_amdgcn_mfma_f32_16x16x32_bf16(ea[0][1], bf1, a0p, 0, 0, 0); \
        a1p = __builtin_amdgcn_mfma_f32_16x16x32_bf16(ea[1][1], bf1, a1p, 0, 0, 0); \
        a0q = __builtin_amdgcn_mfma_f32_16x16x32_bf16(ea[0][3], bf3, a0q, 0, 0, 0); \
        a1q = __builtin_amdgcn_mfma_f32_16x16x32_bf16(ea[1][3], bf3, a1q, 0, 0, 0); \
        const bool act = (t < len);                                            \
        float un[2][4];                                                        \
        un[0][0] = act ? wc[0][0] * (a0p[0] + a0q[0]) : uprev[0][0];           \
        un[0][1] = act ? wc[0][1] * (a0p[1] + a0q[1]) : uprev[0][1];           \
        un[0][2] = act ? wc[0][2] * (a0p[2] + a0q[2]) : uprev[0][2];           \
        un[0][3] = act ? wc[0][3] * (a0p[3] + a0q[3]) : uprev[0][3];           \
        un[1][0] = act ? wc[1][0] * (a1p[0] + a1q[0]) : uprev[1][0];           \
        un[1][1] = act ? wc[1][1] * (a1p[1] + a1q[1]) : uprev[1][1];           \
        un[1][2] = act ? wc[1][2] * (a1p[2] + a1q[2]) : uprev[1][2];           \
        un[1][3] = act ? wc[1][3] * (a1p[3] + a1q[3]) : uprev[1][3];           \
        uprev[0][0] = un[0][0]; uprev[0][1] = un[0][1];                        \
        uprev[0][2] = un[0][2]; uprev[0][3] = un[0][3];                        \
        uprev[1][0] = un[1][0]; uprev[1][1] = un[1][1];                        \
        uprev[1][2] = un[1][2]; uprev[1][3] = un[1][3];                        \
        {                                                                      \
            short4 s4;                                                         \
            s4.x = bf16b(un[0][0]); s4.y = bf16b(un[0][1]);                    \
            s4.z = bf16b(un[0][2]); s4.w = bf16b(un[0][3]);                    \
            *reinterpret_cast<short4*>(&ut[t & 1][g][j0_]) = s4;               \
            s4.x = bf16b(un[1][0]); s4.y = bf16b(un[1][1]);                    \
            s4.z = bf16b(un[1][2]); s4.w = bf16b(un[1][3]);                    \
            *reinterpret_cast<short4*>(&ut[t & 1][g][j0_ + 16]) = s4;          \
        }                                                                      \
        const int sl = ((k_) + 1) & 3;                                         \
        wc[0][0] = __expf(xs[sl][0].x - D9);                                   \
        wc[0][1] = __expf(xs[sl][0].y - D9);                                   \
        wc[0][2] = __expf(xs[sl][0].z - D9);                                   \
        wc[0][3] = __expf(xs[sl][0].w - D9);                                   \
        wc[1][0] = __expf(xs[sl][1].x - D9);                                   \
        wc[1][1] = __expf(xs[sl][1].y - D9);                                   \
        wc[1][2] = __expf(xs[sl][1].z - D9);                                   \
        wc[1][3] = __expf(xs[sl][1].w - D9);                                   \
        {                                                                      \
            int kk = t + 5; if (kk > Tt - 1) kk = Tt - 1;                      \
            xs[sl][0] = *(const float4*)(xb + (size_t)kk * Nn + j0_);          \
            xs[sl][1] = *(const float4*)(xb + (size_t)kk * Nn + j0_ + 16);     \
        }                                                                      \
        if ((k_) == 7) { /* renorm measure */                                  \
            float mm = un[0][0];                                               \
            mm = fmaxf(mm, un[0][1]); mm = fmaxf(mm, un[0][2]);                \
            mm = fmaxf(mm, un[0][3]); mm = fmaxf(mm, un[1][0]);                \
            mm = fmaxf(mm, un[1][1]); mm = fmaxf(mm, un[1][2]);                \
            mm = fmaxf(mm, un[1][3]);                                          \
            mm = fmaxf(mm, __shfl_xor(mm, 16));                                \
            mm = fmaxf(mm, __shfl_xor(mm, 32));                                \
            if (lane < 16) wred[q][lane] = mm;                                 \
        }                                                                      \
        __syncthreads();                                                       \
    }

// ---- FAC per-step body (R6-verified: no barriers, direct-load em ring) ----
#define FAC_STEP(t_, k_)                                                       \
    {                                                                          \
        const int t = (t_);                                                    \
        const int d = ((k_) + 7) & 7;                                          \
        float e0 = em[d][0], e1 = em[d][1], e2 = em[d][2], e3 = em[d][3];      \
        int tn = t + 8; if (tn > Tt - 1) tn = Tt - 1;                          \
        const float* xrow = xb + (size_t)tn * Nn;                              \
        em[d][0] = xrow[tgi[0]]; em[d][1] = xrow[tgi[1]];                      \
        em[d][2] = xrow[tgi[2]]; em[d][3] = xrow[tgi[3]];                      \
        float bup = __shfl_up(bt[3], 1);                                       \
        float prev0 = (lane == 0) ? NEGF : bup;                                \
        float nb[4];                                                           \
        {                                                                      \
            float aa = bt[0] + st[0], bb = prev0 + ntr[0];                     \
            float hi = fmaxf(aa, bb), lo = fminf(aa, bb);                      \
            nb[0] = e0 + hi + __logf(1.0f + __expf(lo - hi));                  \
        }                                                                      \
        {                                                                      \
            float aa = bt[1] + st[1], bb = bt[0] + ntr[1];                     \
            float hi = fmaxf(aa, bb), lo = fminf(aa, bb);                      \
            nb[1] = e1 + hi + __logf(1.0f + __expf(lo - hi));                  \
        }                                                                      \
        {                                                                      \
            float aa = bt[2] + st[2], bb = bt[1] + ntr[2];                     \
            float hi = fmaxf(aa, bb), lo = fminf(aa, bb);                      \
            nb[2] = e2 + hi + __logf(1.0f + __expf(lo - hi));                  \
        }                                                                      \
        {                                                                      \
            float aa = bt[3] + st[3], bb = bt[2] + ntr[3];                     \
            float hi = fmaxf(aa, bb), lo = fminf(aa, bb);                      \
            nb[3] = e3 + hi + __logf(1.0f + __expf(lo - hi));                  \
        }                                                                      \
        if (t < len) {                                                         \
            bt[0] = nb[0]; bt[1] = nb[1]; bt[2] = nb[2]; bt[3] = nb[3];        \
        }                                                                      \
    }

// R12: spread the x stream. blocks 0..31: FCC, FOUR batches each (16 B-cols
// duplicate batch g&3 — MFMA is free, HBM stream per CU drops 8MB -> 2MB).
// blocks 32..95: FAC, 2 batches each (waves 0-1; waves 2-3 exit).
__global__ __launch_bounds__(256) void asg_main(
    const float* __restrict__ trans, const float* __restrict__ x,
    const int* __restrict__ targets, const int* __restrict__ ilen,
    const int* __restrict__ tlen,
    float* __restrict__ fcc_out, float* __restrict__ fac_out)
{
    __shared__ __align__(16) short ut[2][16][136];  // pad 8: 272 B row keeps 16B align
    __shared__ float wred[4][16];

    const int tid  = threadIdx.x;
    const int q    = tid >> 6;
    const int lane = tid & 63;
    const int g    = lane & 15;     // B-col; batch = (blk<<2) + (g&3) (cols duplicated)
    const int quad = lane >> 4;

    if (blockIdx.x < 32) {
        // ================= FCC (4 batches, duplicated across cols) ============
        const int b   = ((int)blockIdx.x << 2) + (g & 3);
        const int len = ilen[b];
        const float* xb = x + (size_t)b * Tt * Nn;

        // E A-frags: wave q owns rows [32q, 32q+32) -> 2 M-tiles of 16 (full E).
        short8 ea[2][4];
        #pragma unroll
        for (int mt = 0; mt < 2; ++mt) {
            const float* tr = trans + (size_t)(32 * q + 16 * mt + g) * Nn + quad * 8;
            #pragma unroll
            for (int kc = 0; kc < 4; ++kc) {
                short8 v;
                #pragma unroll
                for (int jj = 0; jj < 8; ++jj)
                    v[jj] = bf16b(__expf(tr[kc * 32 + jj]));
                ea[mt][kc] = v;
            }
        }

        const int j0_ = 32 * q + 4 * quad;

        // u0 = exp(x[0]) (c = 0); duplicated cols hold duplicated u — benign.
        float uprev[2][4];
        #pragma unroll
        for (int mt = 0; mt < 2; ++mt) {
            const int j0 = j0_ + 16 * mt;
            float4 xv = *(const float4*)(xb + j0);
            uprev[mt][0] = __expf(xv.x); uprev[mt][1] = __expf(xv.y);
            uprev[mt][2] = __expf(xv.z); uprev[mt][3] = __expf(xv.w);
            short4 s4;
            s4.x = bf16b(uprev[mt][0]); s4.y = bf16b(uprev[mt][1]);
            s4.z = bf16b(uprev[mt][2]); s4.w = bf16b(uprev[mt][3]);
            *reinterpret_cast<short4*>(&ut[0][g][j0]) = s4;
        }

        // wc = exp(x[1]-D9); ring xs[k&3] holds x[k], k=2..5 (depth 4)
        float wc[2][4];
        float4 xs[4][2];
        #pragma unroll
        for (int mt = 0; mt < 2; ++mt) {
            const int j0 = j0_ + 16 * mt;
            float4 xv = *(const float4*)(xb + Nn + j0);
            wc[mt][0] = __expf(xv.x - D9); wc[mt][1] = __expf(xv.y - D9);
            wc[mt][2] = __expf(xv.z - D9); wc[mt][3] = __expf(xv.w - D9);
            #pragma unroll
            for (int k = 2; k <= 5; ++k)
                xs[k & 3][mt] = *(const float4*)(xb + (size_t)k * Nn + j0);
        }
        float c = 0.0f;
        __syncthreads();

        #pragma unroll
        for (int k = 1; k < 8; ++k) FCC_STEP(k, k)
        for (int tb = 8; tb < Tt; tb += 8) {
            #pragma unroll
            for (int k = 0; k < 8; ++k) FCC_STEP(tb + k, k)
        }

        // every ACTIVE step multiplies u by exp(-D9); absorb into c once.
        c += D9 * (float)(len - 1);

        float s = 0.f;
        #pragma unroll
        for (int mt = 0; mt < 2; ++mt)
            #pragma unroll
            for (int r = 0; r < 4; ++r) s += uprev[mt][r];
        s += __shfl_xor(s, 16);
        s += __shfl_xor(s, 32);
        if (lane < 16) wred[q][lane] = s;
        __syncthreads();
        if (tid < 4) {   // cols 4..15 are duplicates; write batch = blk*4 + tid
            float tot = wred[0][tid] + wred[1][tid] + wred[2][tid] + wred[3][tid];
            fcc_out[((int)blockIdx.x << 2) + tid] = c + __logf(tot);
        }
    } else {
        // ================= FAC (1 wave per batch, waves 0-1 only) ============
        if (q >= 2) return;
        const int b   = (((int)blockIdx.x - 32) << 1) + q;
        const int len = ilen[b];
        const int tl  = tlen[b];
        const float* xb = x + (size_t)b * Tt * Nn;

        int   tgi[4];
        float st[4], ntr[4], bt[4];
        #pragma unroll
        for (int r = 0; r < 4; ++r) {
            const int s = (lane << 2) + r;
            const int tgv = targets[b * Ss + s];
            const int pg  = (s == 0) ? tgv : targets[b * Ss + s - 1];
            tgi[r] = tgv;
            st[r]  = trans[tgv * Nn + tgv];
            ntr[r] = trans[tgv * Nn + pg];
            bt[r]  = (s == 0) ? xb[tgv] : NEGF;
        }
        float em[8][4];
        #pragma unroll
        for (int k = 1; k <= 8; ++k) {
            int tt = k; if (tt > Tt - 1) tt = Tt - 1;
            const float* xrow = xb + (size_t)tt * Nn;
            em[(k - 1) & 7][0] = xrow[tgi[0]];
            em[(k - 1) & 7][1] = xrow[tgi[1]];
            em[(k - 1) & 7][2] = xrow[tgi[2]];
            em[(k - 1) & 7][3] = xrow[tgi[3]];
        }
        #pragma unroll
        for (int k = 1; k < 8; ++k) FAC_STEP(k, k)
        for (int tb = 8; tb < Tt; tb += 8) {
            #pragma unroll
            for (int k = 0; k < 8; ++k) FAC_STEP(tb + k, k)
        }
        #pragma unroll
        for (int r = 0; r < 4; ++r)
            if ((lane << 2) + r == tl - 1) fac_out[b] = bt[r];
    }
}

__global__ __launch_bounds__(128) void reduce_kernel(const float* __restrict__ fcc,
                                                     const float* __restrict__ fac,
                                                     float* __restrict__ out) {
    __shared__ float r2[2];
    int tid = threadIdx.x;
    float v = fcc[tid] - fac[tid];
    #pragma unroll
    for (int o = 32; o > 0; o >>= 1) v += __shfl_xor(v, o);
    if ((tid & 63) == 0) r2[tid >> 6] = v;
    __syncthreads();
    if (tid == 0) out[0] = (r2[0] + r2[1]) * (1.0f / Bb);
}

extern "C" void kernel_launch(void* const* d_in, const int* in_sizes, int n_in,
                              void* d_out, int out_size, void* d_ws, size_t ws_size,
                              hipStream_t stream) {
    const float* trans   = (const float*)d_in[0];
    const float* x       = (const float*)d_in[1];
    const int*   targets = (const int*)d_in[2];
    const int*   ilen    = (const int*)d_in[3];
    const int*   tlen    = (const int*)d_in[4];
    float* out = (float*)d_out;

    float* fcc = (float*)d_ws;       // 128 floats
    float* fac = fcc + Bb;           // 128 floats

    asg_main<<<96, 256, 0, stream>>>(trans, x, targets, ilen, tlen, fcc, fac);
    reduce_kernel<<<1, 128, 0, stream>>>(fcc, fac, out);
}